// Round 7
// baseline (493.823 us; speedup 1.0000x reference)
//
#include <hip/hip_runtime.h>
#include <stdint.h>
#include <math.h>

#define D_MODEL 1024
#define D_INNER 2048
#define N_RES   1024
#define SEQ     4096
#define BATCH   4
#define M_TOT   (BATCH*SEQ)   // 16384
#define SMEM_BYTES 131072

typedef float f32x4 __attribute__((ext_vector_type(4)));
typedef short bf16x8 __attribute__((ext_vector_type(8)));
typedef unsigned short u16;

__device__ __forceinline__ u16 f2bf(float f) {
  uint32_t u = __builtin_bit_cast(uint32_t, f);
  u += 0x7FFFu + ((u >> 16) & 1u);   // RNE
  return (u16)(u >> 16);
}
__device__ __forceinline__ float bf2f(u16 h) {
  return __builtin_bit_cast(float, (uint32_t)h << 16);
}

__device__ __forceinline__ void g2l16(const void* g, void* l) {
  __builtin_amdgcn_global_load_lds(
      (const __attribute__((address_space(1))) void*)g,
      (__attribute__((address_space(3))) void*)l, 16, 0, 0);
}

// ---------------- f32 -> bf16 convert ----------------
__global__ void cvt_kernel(const float* __restrict__ src, u16* __restrict__ dst, int n4) {
  int stride = gridDim.x * blockDim.x;
  for (int i = blockIdx.x * blockDim.x + threadIdx.x; i < n4; i += stride) {
    f32x4 v = *(const f32x4*)(src + (size_t)i * 4);
    ushort4 o;
    o.x = f2bf(v.x); o.y = f2bf(v.y); o.z = f2bf(v.z); o.w = f2bf(v.w);
    *(ushort4*)(dst + (size_t)i * 4) = o;
  }
}

// ---------------- 256x256 bf16 GEMM, C = A @ B^T  (faithful m201 8-phase) ----
// BK=64, 8 waves (2Mx4N), LDS 128KB: dbuf0 @0 (even K-tiles), dbuf1 @65536
// (odd). Per dbuf: A halves @0/@16384 (128x64 bf16 each), B @32768/@49152.
// Per K-tile 4 phases, 16 MFMA each (quadrant (mh,nh), K=64). Phase body:
// reads; stage; [vmcnt(8) once/K-tile]; s_barrier; lgkmcnt(0); sched_barrier;
// setprio(1); MFMA; setprio(0); s_barrier. Stages: B(t+2)@ph2, A(t+2)@ph3
// (one full barrier after that region's last reads -> WAR-safe). Swizzle:
// LDS chunk = col16 ^ (row&7), source pre-swizzled (rule #21), zero-conflict.
template<int EPI, int K, int NBX>
__global__ __launch_bounds__(512, 2) void gemm256(
    const u16* __restrict__ A, const u16* __restrict__ B,
    void* __restrict__ out0, void* __restrict__ out1,
    const float* __restrict__ bias)
{
  extern __shared__ char smem[];
  constexpr int NITER = K / 128;   // 2 K-tiles per iter
  const int tid  = threadIdx.x;
  const int lane = tid & 63;
  const int wave = tid >> 6;
  const int wm = wave >> 2, wn = wave & 3;

  // XCD-bijective remap (grid % 8 == 0)
  const int nb  = (M_TOT / 256) * NBX;
  const int cpx = nb >> 3;
  const int wg  = ((int)blockIdx.x & 7) * cpx + ((int)blockIdx.x >> 3);
  const int m0 = (wg / NBX) << 8;
  const int n0 = (wg % NBX) << 8;

  // staging source (pre-swizzled): thread covers row t8, chunk (tid&7)^(t8&7)
  const int t8  = tid >> 3;
  const int sw8 = ((tid & 7) ^ (t8 & 7)) << 3;
  const u16* sA = A + (size_t)(m0 + t8) * K + sw8;
  const u16* sB = B + (size_t)(n0 + t8) * K + sw8;
  char* ldsT = smem + tid * 16;

  // fragment read bases: row stride 128 B; chunk(s) = ((s*4+k16)^(l15&7))*16
  const int l15 = lane & 15, k16 = (lane >> 4) & 3;
  const int e7  = l15 & 7;
  const int c0b = (((e7 & 4) + (k16 ^ (e7 & 3))) << 4);  // s=0 chunk byte; s=1: ^64
  const int aBase = wm * 16384 + l15 * 128 + c0b;
  const int bBase = 32768 + (wn >> 1) * 16384 + (((wn & 1) << 6) + l15) * 128 + c0b;

  f32x4 acc[8][4] = {};
  bf16x8 fa[4][2], fb0[2][2], fb1[2][2];

#define STG_A(dn_, colE_) do {                                              \
    g2l16(sA + (colE_),                    ldsT + (dn_) * 65536);           \
    g2l16(sA + (size_t)64  * K + (colE_),  ldsT + (dn_) * 65536 + 8192);    \
    g2l16(sA + (size_t)128 * K + (colE_),  ldsT + (dn_) * 65536 + 16384);   \
    g2l16(sA + (size_t)192 * K + (colE_),  ldsT + (dn_) * 65536 + 24576);   \
  } while (0)
#define STG_B(dn_, colE_) do {                                              \
    g2l16(sB + (colE_),                    ldsT + (dn_) * 65536 + 32768);   \
    g2l16(sB + (size_t)64  * K + (colE_),  ldsT + (dn_) * 65536 + 40960);   \
    g2l16(sB + (size_t)128 * K + (colE_),  ldsT + (dn_) * 65536 + 49152);   \
    g2l16(sB + (size_t)192 * K + (colE_),  ldsT + (dn_) * 65536 + 57344);   \
  } while (0)
#define RD_A(d_, mh_) do {                                                  \
    _Pragma("unroll")                                                       \
    for (int ii = 0; ii < 4; ++ii) {                                        \
      const int o_ = (d_) * 65536 + aBase + (mh_) * 8192 + ii * 2048;       \
      fa[ii][0] = *(const bf16x8*)(smem + o_);                              \
      fa[ii][1] = *(const bf16x8*)(smem + (o_ ^ 64));                       \
    }                                                                       \
  } while (0)
#define RD_B(d_, nh_, FB_) do {                                             \
    _Pragma("unroll")                                                       \
    for (int jj = 0; jj < 2; ++jj) {                                        \
      const int o_ = (d_) * 65536 + bBase + (nh_) * 4096 + jj * 2048;       \
      FB_[jj][0] = *(const bf16x8*)(smem + o_);                             \
      FB_[jj][1] = *(const bf16x8*)(smem + (o_ ^ 64));                      \
    }                                                                       \
  } while (0)
#define SYNC_MFMA(MH_, NH_, FB_) do {                                       \
    __builtin_amdgcn_s_barrier();                                           \
    asm volatile("s_waitcnt lgkmcnt(0)" ::: "memory");                      \
    __builtin_amdgcn_sched_barrier(0);                                      \
    __builtin_amdgcn_s_setprio(1);                                          \
    _Pragma("unroll")                                                       \
    for (int s_ = 0; s_ < 2; ++s_)                                          \
      _Pragma("unroll")                                                     \
      for (int jj = 0; jj < 2; ++jj)                                        \
        _Pragma("unroll")                                                   \
        for (int ii = 0; ii < 4; ++ii)                                      \
          acc[(MH_)*4+ii][(NH_)*2+jj] = __builtin_amdgcn_mfma_f32_16x16x32_bf16( \
              fa[ii][s_], FB_[jj][s_], acc[(MH_)*4+ii][(NH_)*2+jj], 0, 0, 0); \
    __builtin_amdgcn_s_setprio(0);                                          \
    __builtin_amdgcn_sched_barrier(0);                                      \
    __builtin_amdgcn_s_barrier();                                           \
  } while (0)

  // prologue: stage tile0 -> dbuf0, tile1 -> dbuf1; drain tile0 (oldest 8)
  STG_A(0, 0); STG_B(0, 0);
  STG_A(1, 64); STG_B(1, 64);
  asm volatile("s_waitcnt vmcnt(8)" ::: "memory");
  __builtin_amdgcn_s_barrier();

  for (int it = 0; it < NITER; ++it) {
    const int c2 = (it << 7) + 128;   // stage cols for tile 2it+2
    const int c3 = (it << 7) + 192;   // tile 2it+3
    const bool st = (it + 1 < NITER);
    // ---- K-tile 2it (dbuf0) ----
    // ph0: quadrant (0,0)
    RD_A(0, 0); RD_B(0, 0, fb0);
    asm volatile("s_waitcnt lgkmcnt(8)" ::: "memory");
    SYNC_MFMA(0, 0, fb0);
    // ph1: (0,1)
    RD_B(0, 1, fb1);
    SYNC_MFMA(0, 1, fb1);
    // ph2: (1,1); B-region of dbuf0 fully read -> stage B(2it+2)
    RD_A(0, 1);
    if (st) STG_B(0, c2);
    SYNC_MFMA(1, 1, fb1);
    // ph3: (1,0); A-region fully read -> stage A(2it+2); counted vmcnt
    if (st) { STG_A(0, c2); asm volatile("s_waitcnt vmcnt(8)" ::: "memory"); }
    else    {               asm volatile("s_waitcnt vmcnt(0)" ::: "memory"); }
    SYNC_MFMA(1, 0, fb0);
    // ---- K-tile 2it+1 (dbuf1) ----
    // ph4
    RD_A(1, 0); RD_B(1, 0, fb0);
    asm volatile("s_waitcnt lgkmcnt(8)" ::: "memory");
    SYNC_MFMA(0, 0, fb0);
    // ph5
    RD_B(1, 1, fb1);
    SYNC_MFMA(0, 1, fb1);
    // ph6
    RD_A(1, 1);
    if (st) STG_B(1, c3);
    SYNC_MFMA(1, 1, fb1);
    // ph7
    if (st) { STG_A(1, c3); asm volatile("s_waitcnt vmcnt(8)" ::: "memory"); }
    SYNC_MFMA(1, 0, fb0);
  }
#undef STG_A
#undef STG_B
#undef RD_A
#undef RD_B
#undef SYNC_MFMA

  // ---- epilogue: 4 passes of 64x256 f32 LDS transpose -> coalesced IO ----
  // C/D layout: col=lane&15, row=(lane>>4)*4+reg  [verified m89/m91 + rounds 1-6]
  __syncthreads();
  float (*sc)[260] = (float(*)[260])smem;
  const int lr = (lane >> 4) << 2;
  const int lc = lane & 15;
  #pragma unroll
  for (int p = 0; p < 4; ++p) {
    if (wm == (p >> 1)) {
      const int ib = (p & 1) << 2;
      #pragma unroll
      for (int ii = 0; ii < 4; ++ii)
        #pragma unroll
        for (int j = 0; j < 4; ++j)
          #pragma unroll
          for (int r = 0; r < 4; ++r)
            sc[(ii << 4) + lr + r][(wn << 6) + (j << 4) + lc] = acc[ib + ii][j][r];
    }
    __syncthreads();
    #pragma unroll
    for (int rr = 0; rr < 8; ++rr) {
      const int row = (rr << 3) + wave;
      const int col = (tid & 63) << 2;
      const f32x4 v = *(const f32x4*)&sc[row][col];
      const int gr = m0 + (p << 6) + row;
      const int gc = n0 + col;
      if constexpr (EPI == 0) {
        ushort4 o;
        o.x = f2bf(v.x); o.y = f2bf(v.y); o.z = f2bf(v.z); o.w = f2bf(v.w);
        if (n0 < D_INNER)
          *(ushort4*)&((u16*)out0)[(size_t)gr * D_INNER + gc] = o;
        else
          *(ushort4*)&((u16*)out1)[(size_t)gr * N_RES + (gc - D_INNER)] = o;
      } else if constexpr (EPI == 1) {
        const f32x4 b4 = *(const f32x4*)&bias[gc];
        const ushort4 uv = *(const ushort4*)&((const u16*)out1)[(size_t)gr * D_INNER + gc];
        float vv[4] = {v.x, v.y, v.z, v.w};
        float bb[4] = {b4.x, b4.y, b4.z, b4.w};
        u16   uu[4] = {uv.x, uv.y, uv.z, uv.w};
        u16   oo[4];
        #pragma unroll
        for (int q = 0; q < 4; ++q) {
          const float d  = vv[q] + bb[q];
          const float sp = (d > 15.f) ? d : __logf(1.f + __expf(d));
          const float sg = 1.f / (1.f + __expf(-sp));
          oo[q] = f2bf(bf2f(uu[q]) * sg);
        }
        ushort4 o; o.x = oo[0]; o.y = oo[1]; o.z = oo[2]; o.w = oo[3];
        *(ushort4*)&((u16*)out0)[(size_t)gr * D_INNER + gc] = o;
      } else {
        const ushort4 rv = *(const ushort4*)&((const u16*)out1)[(size_t)gr * N_RES + gc];
        f32x4 o;
        o.x = v.x + bf2f(rv.x); o.y = v.y + bf2f(rv.y);
        o.z = v.z + bf2f(rv.z); o.w = v.w + bf2f(rv.w);
        *(f32x4*)&((float*)out0)[(size_t)gr * N_RES + gc] = o;
      }
    }
    __syncthreads();
  }
}

// ---------------- depthwise causal conv (4 taps) ----------------
__global__ __launch_bounds__(256) void conv_kernel(
    const u16* __restrict__ u, u16* __restrict__ uc,
    const float* __restrict__ cw, const float* __restrict__ cb)
{
  const int c0 = threadIdx.x * 8;
  const int b  = blockIdx.x >> 8;
  const int t0 = (blockIdx.x & 255) << 4;
  const size_t base = (size_t)b * SEQ * D_INNER;

  float w0[8], w1[8], w2[8], w3[8], bs[8];
  #pragma unroll
  for (int j = 0; j < 8; ++j) {
    const float* wp = cw + (size_t)(c0 + j) * 4;
    w0[j] = wp[0]; w1[j] = wp[1]; w2[j] = wp[2]; w3[j] = wp[3];
    bs[j] = cb[c0 + j];
  }

  float r0[8], r1[8], r2[8];
  #pragma unroll
  for (int k = 0; k < 3; ++k) {
    const int t = t0 - 3 + k;
    float* rr = (k == 0) ? r0 : (k == 1) ? r1 : r2;
    if (t >= 0) {
      bf16x8 v = *(const bf16x8*)&u[base + (size_t)t * D_INNER + c0];
      #pragma unroll
      for (int j = 0; j < 8; ++j) rr[j] = bf2f((u16)v[j]);
    } else {
      #pragma unroll
      for (int j = 0; j < 8; ++j) rr[j] = 0.f;
    }
  }

  #pragma unroll
  for (int tt = 0; tt < 16; ++tt) {
    const size_t off = base + (size_t)(t0 + tt) * D_INNER + c0;
    bf16x8 v = *(const bf16x8*)&u[off];
    float cur[8];
    #pragma unroll
    for (int j = 0; j < 8; ++j) cur[j] = bf2f((u16)v[j]);
    bf16x8 o;
    #pragma unroll
    for (int j = 0; j < 8; ++j) {
      const float s = bs[j] + w0[j]*r0[j] + w1[j]*r1[j] + w2[j]*r2[j] + w3[j]*cur[j];
      o[j] = (short)f2bf(s);
    }
    *(bf16x8*)&uc[off] = o;
    #pragma unroll
    for (int j = 0; j < 8; ++j) { r0[j] = r1[j]; r1[j] = r2[j]; r2[j] = cur[j]; }
  }
}

// ---------------- chunked IIR scan: y[t] = 0.9 y[t-1] + 0.1 g[t] ----------------
__global__ __launch_bounds__(256) void scan_kernel(const u16* __restrict__ g, u16* __restrict__ y) {
  const int cg    = blockIdx.x & 1;
  const int chunk = (blockIdx.x >> 1) & 63;
  const int b     = blockIdx.x >> 7;
  const int c0 = cg * 1024 + threadIdx.x * 4;
  const int t0 = chunk << 6;
  const size_t base = (size_t)b * SEQ * D_INNER + c0;
  float s0 = 0.f, s1 = 0.f, s2 = 0.f, s3 = 0.f;
  const int tw = (t0 >= 96) ? t0 - 96 : 0;
  for (int t = tw; t < t0; ++t) {
    ushort4 v = *(const ushort4*)&g[base + (size_t)t * D_INNER];
    s0 = s0*0.9f + bf2f(v.x)*0.1f; s1 = s1*0.9f + bf2f(v.y)*0.1f;
    s2 = s2*0.9f + bf2f(v.z)*0.1f; s3 = s3*0.9f + bf2f(v.w)*0.1f;
  }
  for (int t = t0; t < t0 + 64; ++t) {
    ushort4 v = *(const ushort4*)&g[base + (size_t)t * D_INNER];
    s0 = s0*0.9f + bf2f(v.x)*0.1f; s1 = s1*0.9f + bf2f(v.y)*0.1f;
    s2 = s2*0.9f + bf2f(v.z)*0.1f; s3 = s3*0.9f + bf2f(v.w)*0.1f;
    ushort4 o; o.x = f2bf(s0); o.y = f2bf(s1); o.z = f2bf(s2); o.w = f2bf(s3);
    *(ushort4*)&y[base + (size_t)t * D_INNER] = o;
  }
}

extern "C" void kernel_launch(void* const* d_in, const int* in_sizes, int n_in,
                              void* d_out, int out_size, void* d_ws, size_t ws_size,
                              hipStream_t stream) {
  (void)in_sizes; (void)n_in; (void)out_size; (void)ws_size;
  const float* x  = (const float*)d_in[0];
  const float* w1 = (const float*)d_in[1];   // in_proj_w (3072,1024)
  const float* cw = (const float*)d_in[2];   // conv_w (2048,1,4)
  const float* cb = (const float*)d_in[3];   // conv_b (2048,)
  const float* w2 = (const float*)d_in[5];   // dt_proj_w (2048,2048)
  const float* db = (const float*)d_in[6];   // dt_proj_b (2048,)
  const float* w3 = (const float*)d_in[9];   // out_proj_w (1024,2048)
  // d_in[4]=x_proj_w, d_in[7]=A_log, d_in[8]=D are dead in the reference.

  char* ws = (char*)d_ws;
  u16* x_bf   = (u16*)(ws);
  u16* w1_bf  = (u16*)(ws + 33554432);
  u16* w2_bf  = (u16*)(ws + 39845888);
  u16* w3_bf  = (u16*)(ws + 48234496);
  u16* u_bf   = (u16*)(ws + 52428800);       // u, later gated
  u16* res_bf = (u16*)(ws + 119537664);
  u16* uc_bf  = (u16*)(ws + 153092096);      // uc, later y

  hipFuncSetAttribute((const void*)&gemm256<0,1024,12>, hipFuncAttributeMaxDynamicSharedMemorySize, SMEM_BYTES);
  hipFuncSetAttribute((const void*)&gemm256<1,2048,8>,  hipFuncAttributeMaxDynamicSharedMemorySize, SMEM_BYTES);
  hipFuncSetAttribute((const void*)&gemm256<2,2048,4>,  hipFuncAttributeMaxDynamicSharedMemorySize, SMEM_BYTES);

  cvt_kernel<<<2048, 256, 0, stream>>>(x,  x_bf,  M_TOT * D_MODEL / 4);
  cvt_kernel<<<512, 256, 0, stream>>>(w1, w1_bf, 3072 * 1024 / 4);
  cvt_kernel<<<512, 256, 0, stream>>>(w2, w2_bf, 2048 * 2048 / 4);
  cvt_kernel<<<512, 256, 0, stream>>>(w3, w3_bf, 1024 * 2048 / 4);

  // GEMM1: (16384x1024)@(1024x3072)^T -> u / res   (64x12 tiles)
  gemm256<0, 1024, 12><<<768, 512, SMEM_BYTES, stream>>>(x_bf, w1_bf, u_bf, res_bf, nullptr);
  // depthwise causal conv
  conv_kernel<<<1024, 256, 0, stream>>>(u_bf, uc_bf, cw, cb);
  // GEMM2 + bias + softplus + sigmoid + gate -> gated (into u_bf)  (64x8 tiles)
  gemm256<1, 2048, 8><<<512, 512, SMEM_BYTES, stream>>>(uc_bf, w2_bf, u_bf, uc_bf, db);
  // chunked scan -> y (into uc_bf)
  scan_kernel<<<512, 256, 0, stream>>>(u_bf, uc_bf);
  // GEMM3 + res add -> d_out (f32)  (64x4 tiles)
  gemm256<2, 2048, 4><<<256, 512, SMEM_BYTES, stream>>>(uc_bf, w3_bf, d_out, res_bf, nullptr);
}

// Round 8
// 398.717 us; speedup vs baseline: 1.2385x; 1.2385x over previous
//
#include <hip/hip_runtime.h>
#include <stdint.h>
#include <math.h>

#define D_MODEL 1024
#define D_INNER 2048
#define N_RES   1024
#define SEQ     4096
#define BATCH   4
#define M_TOT   (BATCH*SEQ)   // 16384
#define SMEM_BYTES 131072

typedef float f32x4 __attribute__((ext_vector_type(4)));
typedef short bf16x8 __attribute__((ext_vector_type(8)));
typedef unsigned short u16;

__device__ __forceinline__ u16 f2bf(float f) {
  uint32_t u = __builtin_bit_cast(uint32_t, f);
  u += 0x7FFFu + ((u >> 16) & 1u);   // RNE
  return (u16)(u >> 16);
}
__device__ __forceinline__ float bf2f(u16 h) {
  return __builtin_bit_cast(float, (uint32_t)h << 16);
}

__device__ __forceinline__ void g2l16(const void* g, void* l) {
  __builtin_amdgcn_global_load_lds(
      (const __attribute__((address_space(1))) void*)g,
      (__attribute__((address_space(3))) void*)l, 16, 0, 0);
}

// ---------------- fused f32 -> bf16 convert (all 4 tensors, 1 launch) -------
#define CVT_N0 4194304   // x  : 16384*1024/4
#define CVT_N1  786432   // w1 : 3072*1024/4
#define CVT_N2 1048576   // w2 : 2048*2048/4
#define CVT_N3  524288   // w3 : 1024*2048/4
#define CVT_TOT (CVT_N0+CVT_N1+CVT_N2+CVT_N3)

__global__ void cvt_all_kernel(const float* __restrict__ s0, u16* __restrict__ d0,
                               const float* __restrict__ s1, u16* __restrict__ d1,
                               const float* __restrict__ s2, u16* __restrict__ d2,
                               const float* __restrict__ s3, u16* __restrict__ d3) {
  const int stride = gridDim.x * blockDim.x;
  for (int i = blockIdx.x * blockDim.x + threadIdx.x; i < CVT_TOT; i += stride) {
    const float* src; u16* dst; int j = i;
    if (j < CVT_N0) { src = s0; dst = d0; }
    else if ((j -= CVT_N0) < CVT_N1) { src = s1; dst = d1; }
    else if ((j -= CVT_N1) < CVT_N2) { src = s2; dst = d2; }
    else { j -= CVT_N2; src = s3; dst = d3; }
    f32x4 v = *(const f32x4*)(src + (size_t)j * 4);
    ushort4 o;
    o.x = f2bf(v.x); o.y = f2bf(v.y); o.z = f2bf(v.z); o.w = f2bf(v.w);
    *(ushort4*)(dst + (size_t)j * 4) = o;
  }
}

// ---------------- 256x256 bf16 GEMM, C = A @ B^T  (R4 structure, best) ------
// Quad-buffered LDS (BK=32) + register-pipelined fragments: iteration t reads
// tile t+1's fragments (latency hides under tile t's 32-MFMA cluster; compiler
// emits counted lgkm waits), stages tile t+3, waits vmcnt(4) so tile t+1's
// stage has landed. One s_barrier per K-tile. T2 swizzle both-sides.
template<int EPI, int K, int NBX>
__global__ __launch_bounds__(512, 2) void gemm256(
    const u16* __restrict__ A, const u16* __restrict__ B,
    void* __restrict__ out0, void* __restrict__ out1,
    const float* __restrict__ bias)
{
  extern __shared__ char smem[];   // A bufs: 4x16KB @0 ; B bufs: 4x16KB @65536
  constexpr int NT = K / 32;
  const int tid  = threadIdx.x;
  const int lane = tid & 63;
  const int wave = tid >> 6;
  const int wm = wave >> 2, wn = wave & 3;

  // XCD-bijective remap (grid % 8 == 0), n-fastest within chunk
  const int nb  = (M_TOT / 256) * NBX;
  const int cpx = nb >> 3;
  const int wg  = ((int)blockIdx.x & 7) * cpx + ((int)blockIdx.x >> 3);
  const int m0 = (wg / NBX) << 8;
  const int n0 = (wg % NBX) << 8;

  // staging: per gload a wave covers 16 rows x 32k (1024 B LDS linear)
  const int st_row = (wave << 4) + (lane >> 2);
  const int st_kc  = (((lane & 3) ^ ((lane >> 3) & 3)) << 3);  // pre-swizzled k-chunk
  const u16* pA0 = A + (size_t)(m0 + st_row) * K + st_kc;
  const u16* pA1 = pA0 + (size_t)128 * K;
  const u16* pB0 = B + (size_t)(n0 + st_row) * K + st_kc;
  const u16* pB1 = pB0 + (size_t)128 * K;
  const int st_lds = wave << 10;

  // fragment read offsets (row stride 64 B, swizzled 16B chunk)
  const int l15 = lane & 15, k16 = lane >> 4;
  const int chunk = ((k16 ^ ((l15 >> 1) & 3)) << 4);
  const int aoff = (((wm << 7) + l15) << 6) + chunk;
  const int boff = (((wn << 6) + l15) << 6) + chunk;

  f32x4 acc[8][4] = {};
  bf16x8 fa0[8], fb0[4], fa1[8], fb1[4];

#define STAGE(ts_) do {                                   \
    char* ab_ = smem + (((ts_) & 3) << 14);               \
    char* bb_ = smem + 65536 + (((ts_) & 3) << 14);       \
    const int kt_ = (ts_) << 5;                           \
    g2l16(pA0 + kt_, ab_ + st_lds);                       \
    g2l16(pA1 + kt_, ab_ + 8192 + st_lds);                \
    g2l16(pB0 + kt_, bb_ + st_lds);                       \
    g2l16(pB1 + kt_, bb_ + 8192 + st_lds);                \
  } while (0)

#define READF(tr_, RA_, RB_) do {                                   \
    const char* Ab_ = smem + (((tr_) & 3) << 14);                   \
    const char* Bb_ = smem + 65536 + (((tr_) & 3) << 14);           \
    _Pragma("unroll")                                               \
    for (int i_ = 0; i_ < 8; ++i_)                                  \
      RA_[i_] = *(const bf16x8*)(Ab_ + aoff + (i_ << 10));          \
    _Pragma("unroll")                                               \
    for (int j_ = 0; j_ < 4; ++j_)                                  \
      RB_[j_] = *(const bf16x8*)(Bb_ + boff + (j_ << 10));          \
  } while (0)

#define ONE_ITER(t_, RA_, RB_, MA_, MB_) do {                        \
    if ((t_) + 1 < NT) {                                             \
      if ((t_) + 2 < NT) asm volatile("s_waitcnt vmcnt(4)" ::: "memory"); \
      else               asm volatile("s_waitcnt vmcnt(0)" ::: "memory"); \
      __builtin_amdgcn_s_barrier();                                  \
      __builtin_amdgcn_sched_barrier(0);                             \
      READF((t_) + 1, RA_, RB_);                                     \
    }                                                                \
    if ((t_) + 3 < NT) STAGE((t_) + 3);                              \
    __builtin_amdgcn_sched_barrier(0);                               \
    __builtin_amdgcn_s_setprio(1);                                   \
    _Pragma("unroll")                                                \
    for (int j_ = 0; j_ < 4; ++j_) {                                 \
      _Pragma("unroll")                                              \
      for (int i_ = 0; i_ < 8; ++i_)                                 \
        acc[i_][j_] = __builtin_amdgcn_mfma_f32_16x16x32_bf16(MA_[i_], MB_[j_], acc[i_][j_], 0, 0, 0); \
    }                                                                \
    __builtin_amdgcn_s_setprio(0);                                   \
    __builtin_amdgcn_sched_barrier(0);                               \
  } while (0)

  // prologue: stage tiles 0,1,2 (12 gloads); read tile 0 fragments
  #pragma unroll
  for (int pt = 0; pt < 3; ++pt) STAGE(pt);
  asm volatile("s_waitcnt vmcnt(8)" ::: "memory");
  __builtin_amdgcn_s_barrier();
  __builtin_amdgcn_sched_barrier(0);
  READF(0, fa0, fb0);

  for (int t = 0; t < NT; t += 2) {
    ONE_ITER(t,     fa1, fb1, fa0, fb0);
    ONE_ITER(t + 1, fa0, fb0, fa1, fb1);
  }
#undef STAGE
#undef READF
#undef ONE_ITER

  // ---- epilogue: 4 passes of 64x256 f32 LDS transpose -> coalesced IO ----
  // C/D layout: col=lane&15, row=(lane>>4)*4+reg  [verified m89/m91 + rounds 1-7]
  __syncthreads();
  float (*sc)[260] = (float(*)[260])smem;
  const int lr = (lane >> 4) << 2;
  const int lc = lane & 15;
  #pragma unroll
  for (int p = 0; p < 4; ++p) {
    if (wm == (p >> 1)) {
      const int ib = (p & 1) << 2;
      #pragma unroll
      for (int ii = 0; ii < 4; ++ii)
        #pragma unroll
        for (int j = 0; j < 4; ++j)
          #pragma unroll
          for (int r = 0; r < 4; ++r)
            sc[(ii << 4) + lr + r][(wn << 6) + (j << 4) + lc] = acc[ib + ii][j][r];
    }
    __syncthreads();
    #pragma unroll
    for (int rr = 0; rr < 8; ++rr) {
      const int row = (rr << 3) + wave;
      const int col = (tid & 63) << 2;
      const f32x4 v = *(const f32x4*)&sc[row][col];
      const int gr = m0 + (p << 6) + row;
      const int gc = n0 + col;
      if constexpr (EPI == 0) {
        ushort4 o;
        o.x = f2bf(v.x); o.y = f2bf(v.y); o.z = f2bf(v.z); o.w = f2bf(v.w);
        if (n0 < D_INNER)
          *(ushort4*)&((u16*)out0)[(size_t)gr * D_INNER + gc] = o;
        else
          *(ushort4*)&((u16*)out1)[(size_t)gr * N_RES + (gc - D_INNER)] = o;
      } else if constexpr (EPI == 1) {
        const f32x4 b4 = *(const f32x4*)&bias[gc];
        const ushort4 uv = *(const ushort4*)&((const u16*)out1)[(size_t)gr * D_INNER + gc];
        float vv[4] = {v.x, v.y, v.z, v.w};
        float bb[4] = {b4.x, b4.y, b4.z, b4.w};
        u16   uu[4] = {uv.x, uv.y, uv.z, uv.w};
        u16   oo[4];
        #pragma unroll
        for (int q = 0; q < 4; ++q) {
          const float d  = vv[q] + bb[q];
          const float sp = (d > 15.f) ? d : __logf(1.f + __expf(d));
          const float sg = 1.f / (1.f + __expf(-sp));
          oo[q] = f2bf(bf2f(uu[q]) * sg);
        }
        ushort4 o; o.x = oo[0]; o.y = oo[1]; o.z = oo[2]; o.w = oo[3];
        *(ushort4*)&((u16*)out0)[(size_t)gr * D_INNER + gc] = o;
      } else {
        const ushort4 rv = *(const ushort4*)&((const u16*)out1)[(size_t)gr * N_RES + gc];
        f32x4 o;
        o.x = v.x + bf2f(rv.x); o.y = v.y + bf2f(rv.y);
        o.z = v.z + bf2f(rv.z); o.w = v.w + bf2f(rv.w);
        *(f32x4*)&((float*)out0)[(size_t)gr * N_RES + gc] = o;
      }
    }
    __syncthreads();
  }
}

// ---------------- depthwise causal conv (4 taps) ----------------
__global__ __launch_bounds__(256) void conv_kernel(
    const u16* __restrict__ u, u16* __restrict__ uc,
    const float* __restrict__ cw, const float* __restrict__ cb)
{
  const int c0 = threadIdx.x * 8;
  const int b  = blockIdx.x >> 8;
  const int t0 = (blockIdx.x & 255) << 4;
  const size_t base = (size_t)b * SEQ * D_INNER;

  float w0[8], w1[8], w2[8], w3[8], bs[8];
  #pragma unroll
  for (int j = 0; j < 8; ++j) {
    const float* wp = cw + (size_t)(c0 + j) * 4;
    w0[j] = wp[0]; w1[j] = wp[1]; w2[j] = wp[2]; w3[j] = wp[3];
    bs[j] = cb[c0 + j];
  }

  float r0[8], r1[8], r2[8];
  #pragma unroll
  for (int k = 0; k < 3; ++k) {
    const int t = t0 - 3 + k;
    float* rr = (k == 0) ? r0 : (k == 1) ? r1 : r2;
    if (t >= 0) {
      bf16x8 v = *(const bf16x8*)&u[base + (size_t)t * D_INNER + c0];
      #pragma unroll
      for (int j = 0; j < 8; ++j) rr[j] = bf2f((u16)v[j]);
    } else {
      #pragma unroll
      for (int j = 0; j < 8; ++j) rr[j] = 0.f;
    }
  }

  #pragma unroll
  for (int tt = 0; tt < 16; ++tt) {
    const size_t off = base + (size_t)(t0 + tt) * D_INNER + c0;
    bf16x8 v = *(const bf16x8*)&u[off];
    float cur[8];
    #pragma unroll
    for (int j = 0; j < 8; ++j) cur[j] = bf2f((u16)v[j]);
    bf16x8 o;
    #pragma unroll
    for (int j = 0; j < 8; ++j) {
      const float s = bs[j] + w0[j]*r0[j] + w1[j]*r1[j] + w2[j]*r2[j] + w3[j]*cur[j];
      o[j] = (short)f2bf(s);
    }
    *(bf16x8*)&uc[off] = o;
    #pragma unroll
    for (int j = 0; j < 8; ++j) { r0[j] = r1[j]; r1[j] = r2[j]; r2[j] = cur[j]; }
  }
}

// ---------------- chunked IIR scan: y[t] = 0.9 y[t-1] + 0.1 g[t] ----------------
// chunk=128, warm-up=96 (0.9^96 ~ 4e-5 -> negligible at bf16 tolerance)
__global__ __launch_bounds__(256) void scan_kernel(const u16* __restrict__ g, u16* __restrict__ y) {
  const int cg    = blockIdx.x & 1;
  const int chunk = (blockIdx.x >> 1) & 31;    // 32 chunks of 128
  const int b     = blockIdx.x >> 6;
  const int c0 = cg * 1024 + threadIdx.x * 4;
  const int t0 = chunk << 7;
  const size_t base = (size_t)b * SEQ * D_INNER + c0;
  float s0 = 0.f, s1 = 0.f, s2 = 0.f, s3 = 0.f;
  const int tw = (t0 >= 96) ? t0 - 96 : 0;
  for (int t = tw; t < t0; ++t) {
    ushort4 v = *(const ushort4*)&g[base + (size_t)t * D_INNER];
    s0 = s0*0.9f + bf2f(v.x)*0.1f; s1 = s1*0.9f + bf2f(v.y)*0.1f;
    s2 = s2*0.9f + bf2f(v.z)*0.1f; s3 = s3*0.9f + bf2f(v.w)*0.1f;
  }
  for (int t = t0; t < t0 + 128; ++t) {
    ushort4 v = *(const ushort4*)&g[base + (size_t)t * D_INNER];
    s0 = s0*0.9f + bf2f(v.x)*0.1f; s1 = s1*0.9f + bf2f(v.y)*0.1f;
    s2 = s2*0.9f + bf2f(v.z)*0.1f; s3 = s3*0.9f + bf2f(v.w)*0.1f;
    ushort4 o; o.x = f2bf(s0); o.y = f2bf(s1); o.z = f2bf(s2); o.w = f2bf(s3);
    *(ushort4*)&y[base + (size_t)t * D_INNER] = o;
  }
}

extern "C" void kernel_launch(void* const* d_in, const int* in_sizes, int n_in,
                              void* d_out, int out_size, void* d_ws, size_t ws_size,
                              hipStream_t stream) {
  (void)in_sizes; (void)n_in; (void)out_size; (void)ws_size;
  const float* x  = (const float*)d_in[0];
  const float* w1 = (const float*)d_in[1];   // in_proj_w (3072,1024)
  const float* cw = (const float*)d_in[2];   // conv_w (2048,1,4)
  const float* cb = (const float*)d_in[3];   // conv_b (2048,)
  const float* w2 = (const float*)d_in[5];   // dt_proj_w (2048,2048)
  const float* db = (const float*)d_in[6];   // dt_proj_b (2048,)
  const float* w3 = (const float*)d_in[9];   // out_proj_w (1024,2048)
  // d_in[4]=x_proj_w, d_in[7]=A_log, d_in[8]=D are dead in the reference.

  char* ws = (char*)d_ws;
  u16* x_bf   = (u16*)(ws);
  u16* w1_bf  = (u16*)(ws + 33554432);
  u16* w2_bf  = (u16*)(ws + 39845888);
  u16* w3_bf  = (u16*)(ws + 48234496);
  u16* u_bf   = (u16*)(ws + 52428800);       // u, later gated
  u16* res_bf = (u16*)(ws + 119537664);
  u16* uc_bf  = (u16*)(ws + 153092096);      // uc, later y

  hipFuncSetAttribute((const void*)&gemm256<0,1024,12>, hipFuncAttributeMaxDynamicSharedMemorySize, SMEM_BYTES);
  hipFuncSetAttribute((const void*)&gemm256<1,2048,8>,  hipFuncAttributeMaxDynamicSharedMemorySize, SMEM_BYTES);
  hipFuncSetAttribute((const void*)&gemm256<2,2048,4>,  hipFuncAttributeMaxDynamicSharedMemorySize, SMEM_BYTES);

  // all f32->bf16 conversions in one launch
  cvt_all_kernel<<<2048, 256, 0, stream>>>(x, x_bf, w1, w1_bf, w2, w2_bf, w3, w3_bf);

  // GEMM1: (16384x1024)@(1024x3072)^T -> u / res   (64x12 tiles)
  gemm256<0, 1024, 12><<<768, 512, SMEM_BYTES, stream>>>(x_bf, w1_bf, u_bf, res_bf, nullptr);
  // depthwise causal conv
  conv_kernel<<<1024, 256, 0, stream>>>(u_bf, uc_bf, cw, cb);
  // GEMM2 + bias + softplus + sigmoid + gate -> gated (into u_bf)  (64x8 tiles)
  gemm256<1, 2048, 8><<<512, 512, SMEM_BYTES, stream>>>(uc_bf, w2_bf, u_bf, uc_bf, db);
  // chunked scan -> y (into uc_bf)
  scan_kernel<<<256, 256, 0, stream>>>(u_bf, uc_bf);
  // GEMM3 + res add -> d_out (f32)  (64x4 tiles)
  gemm256<2, 2048, 4><<<256, 512, SMEM_BYTES, stream>>>(uc_bf, w3_bf, d_out, res_bf, nullptr);
}